// Round 7
// baseline (447.714 us; speedup 1.0000x reference)
//
#include <hip/hip_runtime.h>
#include <hip/hip_bf16.h>
#include <math.h>

// Fused conv3x3(64->64) + bias + min_k + tanh(tanh()) via bf16 MFMA implicit GEMM.
// x: [16,64,256,256] f32, w: [64,64,3,3] f32, b: [64] f32, out: [16,1,256,256] f32
//
// Round 7: occupancy attack. sB eliminated (B-frags direct from global wB — pattern
//   verified in r3; 72 KB stays L2/L1-resident). LDS = sA only (28.8 KB). A-frag
//   burst shrunk to 12 (per-r reload) to cut live VGPRs. __launch_bounds__(256,3)
//   -> 3 blocks/CU (12 waves) vs r6's 2 (8 waves): staging of one block overlaps
//   compute of the other two.
// mfma_f32_16x16x32_bf16: A[m=lane&15][k=(lane>>4)*8+j], B[k=(lane>>4)*8+j][n=lane&15],
//                         C/D col=lane&15, row=(lane>>4)*4+reg (HW-verified r2-r6).

typedef __bf16 bf16x8 __attribute__((ext_vector_type(8)));
typedef float f32x4 __attribute__((ext_vector_type(4)));

#define WB_ELEMS (64 * 64 * 9)
#define SA_PX   40                      // elements per pixel slot (32 used + 8 pad)
#define SA_ROW  (20 * SA_PX)            // 800 elements per row (20 px)

// ---- weight prep: w[k][c][tap] -> wB[(((chunk*9+tap)*4+nt)*64+lane)*8+j] ----
__global__ __launch_bounds__(256)
void conv_prep_w(const float* __restrict__ w, __bf16* __restrict__ wB) {
    int idx = blockIdx.x * 256 + threadIdx.x;
    if (idx >= WB_ELEMS) return;
    int k   = idx / 576;
    int rem = idx - k * 576;
    int c   = rem / 9;
    int tap = rem - c * 9;
    int nt = k >> 4, m15 = k & 15;
    int chunk = c >> 5, q = (c >> 3) & 3, j = c & 7;
    int lane = (q << 4) | m15;
    wB[((((chunk * 9 + tap) * 4 + nt) * 64 + lane) << 3) + j] = (__bf16)w[idx];
}

// ---- fused: stage(global fp32 -> LDS bf16, transposed) + MFMA + min/tanh epilogue ----
__global__ __launch_bounds__(256, 3)
void conv_min_tanh_fused(const float* __restrict__ x,
                         const __bf16* __restrict__ wB,
                         const float* __restrict__ b,
                         float* __restrict__ out)
{
    __shared__ __attribute__((aligned(16))) __bf16 sA[18 * SA_ROW];     // 28800 B

    const int tid  = threadIdx.x;
    const int lane = tid & 63;
    const int wave = tid >> 6;
    const int n    = blockIdx.z;
    const int h0   = blockIdx.y * 16;
    const int w0   = blockIdx.x * 16;
    const int m15  = lane & 15;
    const int q    = lane >> 4;

    f32x4 acc[4][4];  // [mt][nt]
#pragma unroll
    for (int mt = 0; mt < 4; ++mt)
#pragma unroll
        for (int nt = 0; nt < 4; ++nt)
            acc[mt][nt] = (f32x4){0.f, 0.f, 0.f, 0.f};

#pragma unroll 1
    for (int chunk = 0; chunk < 2; ++chunk) {
        if (chunk) __syncthreads();          // all reads of chunk-0 sA done

        // ---- stage A: halo rows h0-1..h0+16, px w0-1..w0+18, c chunk*32..+32 ----
        // slot = row*20 + span*4 + cg ; each slot: 4 px (span) x 8 c (cg)
        for (int slot = tid; slot < 360; slot += 256) {
            const int row  = slot / 20;
            const int rem  = slot - row * 20;
            const int span = rem >> 2;
            const int cg   = rem & 3;
            const int gh   = h0 + row - 1;
            const int gw0  = w0 - 1 + span * 4;

            f32x4 v[8];
            if ((unsigned)gh < 256u) {
                const float* src = x + (size_t)(n * 64 + chunk * 32 + cg * 8) * 65536
                                     + (size_t)gh * 256;
                if (gw0 >= 0 && gw0 <= 252) {
#pragma unroll
                    for (int j = 0; j < 8; ++j)
                        v[j] = *(const f32x4*)&src[(size_t)j * 65536 + gw0];
                } else {
#pragma unroll
                    for (int j = 0; j < 8; ++j)
#pragma unroll
                        for (int i = 0; i < 4; ++i) {
                            const int gw = gw0 + i;
                            v[j][i] = ((unsigned)gw < 256u) ? src[(size_t)j * 65536 + gw] : 0.f;
                        }
                }
            } else {
#pragma unroll
                for (int j = 0; j < 8; ++j)
                    v[j] = (f32x4){0.f, 0.f, 0.f, 0.f};
            }
            __bf16* wp = &sA[row * SA_ROW + (span * 4) * SA_PX + cg * 8];
#pragma unroll
            for (int i = 0; i < 4; ++i) {
                bf16x8 o;
                o[0] = (__bf16)v[0][i]; o[1] = (__bf16)v[1][i];
                o[2] = (__bf16)v[2][i]; o[3] = (__bf16)v[3][i];
                o[4] = (__bf16)v[4][i]; o[5] = (__bf16)v[5][i];
                o[6] = (__bf16)v[6][i]; o[7] = (__bf16)v[7][i];
                *(bf16x8*)&wp[i * SA_PX] = o;
            }
        }
        __syncthreads();

        const __bf16* wBc = wB + chunk * (9 * 4 * 64 * 8);
#pragma unroll
        for (int r = 0; r < 3; ++r) {
            // A fragments for this r: rows wave*4+r .. +3, s 0..2
            bf16x8 af[4][3];
#pragma unroll
            for (int i = 0; i < 4; ++i)
#pragma unroll
                for (int s = 0; s < 3; ++s)
                    af[i][s] = *(const bf16x8*)
                        &sA[(wave * 4 + r + i) * SA_ROW + (m15 + s) * SA_PX + q * 8];
#pragma unroll
            for (int s = 0; s < 3; ++s) {
                const int tap = r * 3 + s;
                bf16x8 bf[4];
#pragma unroll
                for (int nt = 0; nt < 4; ++nt)
                    bf[nt] = *(const bf16x8*)&wBc[((tap * 4 + nt) * 64 + lane) << 3];
#pragma unroll
                for (int mt = 0; mt < 4; ++mt)
#pragma unroll
                    for (int nt = 0; nt < 4; ++nt)
                        acc[mt][nt] = __builtin_amdgcn_mfma_f32_16x16x32_bf16(
                            af[mt][s], bf[nt], acc[mt][nt], 0, 0, 0);
            }
        }
    }

    // ---- epilogue: +bias, min over 64 k, tanh(tanh), store (verified r2-r6) ----
    float bias[4];
#pragma unroll
    for (int nt = 0; nt < 4; ++nt) bias[nt] = b[nt * 16 + m15];

#pragma unroll
    for (int mt = 0; mt < 4; ++mt) {
        float mv[4];
#pragma unroll
        for (int reg = 0; reg < 4; ++reg) {
            float v = acc[mt][0][reg] + bias[0];
            v = fminf(v, acc[mt][1][reg] + bias[1]);
            v = fminf(v, acc[mt][2][reg] + bias[2]);
            v = fminf(v, acc[mt][3][reg] + bias[3]);
            v = fminf(v, __shfl_xor(v, 1));
            v = fminf(v, __shfl_xor(v, 2));
            v = fminf(v, __shfl_xor(v, 4));
            v = fminf(v, __shfl_xor(v, 8));
            mv[reg] = v;
        }
        const int r2 = lane & 3;
        float v = mv[0];
        v = (r2 == 1) ? mv[1] : v;
        v = (r2 == 2) ? mv[2] : v;
        v = (r2 == 3) ? mv[3] : v;
        v = tanhf(tanhf(v));
        if (m15 < 4) {
            const int pix = q * 4 + r2;
            const int gh  = h0 + wave * 4 + mt;
            const int gw  = w0 + pix;
            out[((size_t)n * 256 + gh) * 256 + gw] = v;
        }
    }
}

extern "C" void kernel_launch(void* const* d_in, const int* in_sizes, int n_in,
                              void* d_out, int out_size, void* d_ws, size_t ws_size,
                              hipStream_t stream) {
    const float* x = (const float*)d_in[0];
    const float* w = (const float*)d_in[1];
    const float* b = (const float*)d_in[2];
    float* out = (float*)d_out;
    __bf16* wB = (__bf16*)d_ws;  // 73728 B

    conv_prep_w<<<dim3(144), dim3(256), 0, stream>>>(w, wB);
    conv_min_tanh_fused<<<dim3(16, 16, 16), dim3(256), 0, stream>>>(x, wB, b, out);
}